// Round 9
// baseline (315.911 us; speedup 1.0000x reference)
//
#include <hip/hip_runtime.h>

namespace {
constexpr int kB = 16;
constexpr int kN = 131072;            // 2^17
constexpr int kNLog = 17;
constexpr int kCMid = 128;
constexpr int kCOut = 16;
constexpr int kCells32Log = 15;       // 32^3
constexpr int kCells64Log = 18;       // 64^3
constexpr int kCells32 = 1 << kCells32Log;
constexpr int kCells64 = 1 << kCells64Log;
constexpr long kOut32Elems = (long)kB * kCOut * kCells32;
constexpr int kChunks32 = 16;         // point-chunks per batch for win32
constexpr int kSlabs64 = 16;          // ix-slabs per batch for win64
constexpr int kSlabCells = kCells64 / kSlabs64;  // 16384
}  // namespace

__device__ inline unsigned int packbf2(float lo, float hi) {
    unsigned int a = __float_as_uint(lo);
    unsigned int b = __float_as_uint(hi);
    a = (a + 0x7FFFu + ((a >> 16) & 1u)) >> 16;
    b = (b + 0x7FFFu + ((b >> 16) & 1u)) & 0xFFFF0000u;
    return b | a;
}
__device__ inline float bf_lo(unsigned int p) { return __uint_as_float(p << 16); }
__device__ inline float bf_hi(unsigned int p) { return __uint_as_float(p & 0xFFFF0000u); }

// ---------------------------------------------------------------------------
// Stage packed weights: W1p[k][4]=(w0,w1,w2,b1k); W2t[k][16]. Uniform float4
// reads -> s_load broadcasts in the MLP loop (verified R3/R4: SGPR 80-96).
// ---------------------------------------------------------------------------
__global__ __launch_bounds__(256) void k_pack(
    const float* __restrict__ W1, const float* __restrict__ b1,
    const float* __restrict__ W2,
    float* __restrict__ W1p, float* __restrict__ W2t)
{
    const int t = threadIdx.x;
    for (int k = t; k < kCMid; k += 256) {
        W1p[k * 4 + 0] = W1[k * 3 + 0];
        W1p[k * 4 + 1] = W1[k * 3 + 1];
        W1p[k * 4 + 2] = W1[k * 3 + 2];
        W1p[k * 4 + 3] = b1[k];
    }
    for (int idx = t; idx < kCOut * kCMid; idx += 256) {
        const int c = idx >> 7;
        const int k = idx & 127;
        W2t[k * kCOut + c] = W2[idx];
    }
}

// ---------------------------------------------------------------------------
// Permuted-order precompute (NO atomics): for (b,i): j=perm[b,i];
// prec[b][j] = cell64<<33 | cell32<<18 | (i+1).  pri needs 18 bits (max 2^17).
// Bijective scatter write, L2-resident. Replaces k_inv AND removes all
// global atomics from the pipeline (R8 diagnosis: 4.2M fabric atomics = 190us
// wall that block-placement cannot fix).
// Cell math: __fmul_rn/__fadd_rn (no FMA contraction) matches numpy exactly.
// ---------------------------------------------------------------------------
__global__ __launch_bounds__(256) void k_prec(
    const float* __restrict__ x,
    const int* __restrict__ perm,
    unsigned long long* __restrict__ prec)
{
    const long gid = (long)blockIdx.x * 256 + threadIdx.x;  // over B*N permuted
    const long bbase = gid & ~(long)(kN - 1);               // b*kN
    const int i = (int)(gid & (kN - 1));
    const int j = perm[gid];

    const float* xp = x + (bbase + j) * 3;
    const float v0 = xp[0], v1 = xp[1], v2 = xp[2];

    const int ix32 = (int)fminf(fmaxf(__fadd_rn(__fmul_rn(v0, 32.0f), 16.5f), 0.0f), 31.0f);
    const int iy32 = (int)fminf(fmaxf(__fadd_rn(__fmul_rn(v1, 32.0f), 16.5f), 0.0f), 31.0f);
    const int iz32 = (int)fminf(fmaxf(__fadd_rn(__fmul_rn(v2, 32.0f), 16.5f), 0.0f), 31.0f);
    const int ix64 = (int)fminf(fmaxf(__fadd_rn(__fmul_rn(v0, 64.0f), 32.5f), 0.0f), 63.0f);
    const int iy64 = (int)fminf(fmaxf(__fadd_rn(__fmul_rn(v1, 64.0f), 32.5f), 0.0f), 63.0f);
    const int iz64 = (int)fminf(fmaxf(__fadd_rn(__fmul_rn(v2, 64.0f), 32.5f), 0.0f), 63.0f);

    const unsigned long long cell32 = (unsigned long long)((ix32 * 32 + iy32) * 32 + iz32);
    const unsigned long long cell64 = (unsigned long long)((ix64 * 64 + iy64) * 64 + iz64);
    prec[bbase + j] = (cell64 << 33) | (cell32 << 18) | (unsigned long long)(i + 1);
}

// ---------------------------------------------------------------------------
// Dense MLP in natural order, 2 pts/thread (R5 structure, proven correct):
// coalesced x, weights via uniform s_load, feat[b,j] = 16 bf16 (32B).
// Pure VALU + streaming -- no atomics, no gathers.
// ---------------------------------------------------------------------------
__global__ __launch_bounds__(256, 4) void k_mlp(
    const float* __restrict__ x,
    const float* __restrict__ W1p, const float* __restrict__ W2t,
    const float* __restrict__ b2,
    uint4* __restrict__ feat)
{
    const long pair = (long)blockIdx.x * 256 + threadIdx.x;  // over B*N/2
    const long p0 = pair * 2;

    const float2 xa = *(const float2*)(x + p0 * 3 + 0);
    const float2 xb = *(const float2*)(x + p0 * 3 + 2);
    const float2 xc = *(const float2*)(x + p0 * 3 + 4);
    const float x00 = xa.x, x01 = xa.y, x02 = xb.x;
    const float x10 = xb.y, x11 = xc.x, x12 = xc.y;

    float acc0[kCOut], acc1[kCOut];
    #pragma unroll
    for (int c = 0; c < kCOut; ++c) { acc0[c] = 0.0f; acc1[c] = 0.0f; }

    const float4* __restrict__ w1v = (const float4*)W1p;
    const float4* __restrict__ w2v = (const float4*)W2t;

    #pragma unroll 4
    for (int k = 0; k < kCMid; ++k) {
        const float4 w1 = w1v[k];
        const float h0 = fmaxf(fmaf(w1.x, x00, fmaf(w1.y, x01, fmaf(w1.z, x02, w1.w))), 0.0f);
        const float h1 = fmaxf(fmaf(w1.x, x10, fmaf(w1.y, x11, fmaf(w1.z, x12, w1.w))), 0.0f);
        #pragma unroll
        for (int q = 0; q < 4; ++q) {
            const float4 wq = w2v[k * 4 + q];
            acc0[4 * q + 0] = fmaf(wq.x, h0, acc0[4 * q + 0]);
            acc0[4 * q + 1] = fmaf(wq.y, h0, acc0[4 * q + 1]);
            acc0[4 * q + 2] = fmaf(wq.z, h0, acc0[4 * q + 2]);
            acc0[4 * q + 3] = fmaf(wq.w, h0, acc0[4 * q + 3]);
            acc1[4 * q + 0] = fmaf(wq.x, h1, acc1[4 * q + 0]);
            acc1[4 * q + 1] = fmaf(wq.y, h1, acc1[4 * q + 1]);
            acc1[4 * q + 2] = fmaf(wq.z, h1, acc1[4 * q + 2]);
            acc1[4 * q + 3] = fmaf(wq.w, h1, acc1[4 * q + 3]);
        }
    }

    const float4 bq0 = ((const float4*)b2)[0];
    const float4 bq1 = ((const float4*)b2)[1];
    const float4 bq2 = ((const float4*)b2)[2];
    const float4 bq3 = ((const float4*)b2)[3];

    uint4 f;
    f.x = packbf2(acc0[0]  + bq0.x, acc0[1]  + bq0.y);
    f.y = packbf2(acc0[2]  + bq0.z, acc0[3]  + bq0.w);
    f.z = packbf2(acc0[4]  + bq1.x, acc0[5]  + bq1.y);
    f.w = packbf2(acc0[6]  + bq1.z, acc0[7]  + bq1.w);
    feat[p0 * 2 + 0] = f;
    f.x = packbf2(acc0[8]  + bq2.x, acc0[9]  + bq2.y);
    f.y = packbf2(acc0[10] + bq2.z, acc0[11] + bq2.w);
    f.z = packbf2(acc0[12] + bq3.x, acc0[13] + bq3.y);
    f.w = packbf2(acc0[14] + bq3.z, acc0[15] + bq3.w);
    feat[p0 * 2 + 1] = f;
    f.x = packbf2(acc1[0]  + bq0.x, acc1[1]  + bq0.y);
    f.y = packbf2(acc1[2]  + bq0.z, acc1[3]  + bq0.w);
    f.z = packbf2(acc1[4]  + bq1.x, acc1[5]  + bq1.y);
    f.w = packbf2(acc1[6]  + bq1.z, acc1[7]  + bq1.w);
    feat[p0 * 2 + 2] = f;
    f.x = packbf2(acc1[8]  + bq2.x, acc1[9]  + bq2.y);
    f.y = packbf2(acc1[10] + bq2.z, acc1[11] + bq2.w);
    f.z = packbf2(acc1[12] + bq3.x, acc1[13] + bq3.y);
    f.w = packbf2(acc1[14] + bq3.z, acc1[15] + bq3.w);
    feat[p0 * 2 + 3] = f;
}

// ---------------------------------------------------------------------------
// win32 via LDS: block = (batch b, point-chunk c). Full 32768-cell winner
// array (u32 pri tokens) in 128 KB LDS; ds-atomicMax per point; plain
// coalesced writeout of the partial. Merge happens inline in k_gather32.
// ---------------------------------------------------------------------------
__global__ __launch_bounds__(1024) void k_win32(
    const unsigned long long* __restrict__ prec,
    unsigned int* __restrict__ partial32)
{
    __shared__ unsigned int lwin[kCells32];   // 128 KB
    const int b = blockIdx.x >> 4;
    const int c = blockIdx.x & (kChunks32 - 1);
    const int t = threadIdx.x;

    #pragma unroll
    for (int r = 0; r < kCells32 / 1024; ++r) lwin[r * 1024 + t] = 0u;
    __syncthreads();

    const long base = ((long)b << kNLog) + (long)c * (kN / kChunks32);
    #pragma unroll
    for (int r = 0; r < (kN / kChunks32) / 1024; ++r) {   // 8 iters
        const unsigned long long w = prec[base + r * 1024 + t];
        atomicMax(&lwin[(int)((w >> 18) & 0x7FFFull)], (unsigned int)(w & 0x3FFFFull));
    }
    __syncthreads();

    unsigned int* dst = partial32 + ((long)blockIdx.x << kCells32Log);
    #pragma unroll
    for (int r = 0; r < kCells32 / 1024; ++r) dst[r * 1024 + t] = lwin[r * 1024 + t];
}

// ---------------------------------------------------------------------------
// win64 via LDS slabs: block = (batch b, ix-slab s of 16384 contiguous
// cells). u64 tokens (pri<<32)|j in 128 KB LDS. Each block rescans its
// batch's prec (1 MB, L2/L3-resident), filters to its slab, LDS-atomics,
// then exclusively owns + coalesced-writes its slab. No merge, no zero,
// no global atomics.
// ---------------------------------------------------------------------------
__global__ __launch_bounds__(1024) void k_win64(
    const unsigned long long* __restrict__ prec,
    unsigned long long* __restrict__ win64)
{
    __shared__ unsigned long long lwin[kSlabCells];   // 128 KB
    const int b = blockIdx.x >> 4;
    const int s = blockIdx.x & (kSlabs64 - 1);
    const int t = threadIdx.x;

    #pragma unroll
    for (int r = 0; r < kSlabCells / 1024; ++r) lwin[r * 1024 + t] = 0ull;
    __syncthreads();

    const long base = (long)b << kNLog;
    for (int r = 0; r < kN / 1024; ++r) {             // 128 iters
        const int j = r * 1024 + t;
        const unsigned long long w = prec[base + j];
        const int cell = (int)(w >> 33);
        if ((cell >> 14) == s)
            atomicMax(&lwin[cell & (kSlabCells - 1)],
                      ((w & 0x3FFFFull) << 32) | (unsigned long long)(unsigned int)j);
    }
    __syncthreads();

    unsigned long long* dst = win64 + ((long)b << kCells64Log) + ((long)s << 14);
    #pragma unroll
    for (int r = 0; r < kSlabCells / 1024; ++r) dst[r * 1024 + t] = lwin[r * 1024 + t];
}

// ---------------------------------------------------------------------------
// gather32 with inline 16-way partial merge: w = max_c partial32[b][c][cell]
// (16 coalesced streams); i = w-1 -> j = perm[b,i] (L2 hop) -> feat[b,j].
// Writes all 16 channels (zeros if empty) -- full rewrite every call.
// ---------------------------------------------------------------------------
__global__ __launch_bounds__(256) void k_gather32(
    const unsigned int* __restrict__ partial32,
    const int* __restrict__ perm,
    const uint4* __restrict__ feat,
    float* __restrict__ out)
{
    const long gid = (long)blockIdx.x * 256 + threadIdx.x;  // over B*cells32
    const int b = (int)(gid >> kCells32Log);
    const int cell = (int)(gid & (kCells32 - 1));

    unsigned int w = 0u;
    #pragma unroll
    for (int c = 0; c < kChunks32; ++c)
        w = max(w, partial32[(((long)(b * kChunks32 + c)) << kCells32Log) + cell]);

    float v[kCOut];
    #pragma unroll
    for (int c = 0; c < kCOut; ++c) v[c] = 0.0f;

    if (w != 0u) {
        const int i = (int)(w - 1u);
        const int j = perm[((long)b << kNLog) + i];
        const long pidx = ((long)b << kNLog) + j;
        const uint4 f0 = feat[pidx * 2 + 0];
        const uint4 f1 = feat[pidx * 2 + 1];
        v[0]  = bf_lo(f0.x); v[1]  = bf_hi(f0.x);
        v[2]  = bf_lo(f0.y); v[3]  = bf_hi(f0.y);
        v[4]  = bf_lo(f0.z); v[5]  = bf_hi(f0.z);
        v[6]  = bf_lo(f0.w); v[7]  = bf_hi(f0.w);
        v[8]  = bf_lo(f1.x); v[9]  = bf_hi(f1.x);
        v[10] = bf_lo(f1.y); v[11] = bf_hi(f1.y);
        v[12] = bf_lo(f1.z); v[13] = bf_hi(f1.z);
        v[14] = bf_lo(f1.w); v[15] = bf_hi(f1.w);
    }

    float* op = out + (((long)b * kCOut) << kCells32Log) + cell;
    #pragma unroll
    for (int c = 0; c < kCOut; ++c) op[(long)c << kCells32Log] = v[c];
}

// ---------------------------------------------------------------------------
// gather64: token (pri<<32)|j read coalesced; j -> feat[b,j] (random 32B,
// L3-resident); write 16 channels (zeros if empty).
// ---------------------------------------------------------------------------
__global__ __launch_bounds__(256) void k_gather64(
    const unsigned long long* __restrict__ win,
    const uint4* __restrict__ feat,
    float* __restrict__ out)
{
    const long gid = (long)blockIdx.x * 256 + threadIdx.x;  // over B*cells64
    const int b = (int)(gid >> kCells64Log);
    const int cell = (int)(gid & (kCells64 - 1));
    const unsigned long long w = win[gid];

    float v[kCOut];
    #pragma unroll
    for (int c = 0; c < kCOut; ++c) v[c] = 0.0f;

    if (w != 0ull) {
        const int j = (int)(w & 0xFFFFFFFFull);
        const long pidx = ((long)b << kNLog) + j;
        const uint4 f0 = feat[pidx * 2 + 0];
        const uint4 f1 = feat[pidx * 2 + 1];
        v[0]  = bf_lo(f0.x); v[1]  = bf_hi(f0.x);
        v[2]  = bf_lo(f0.y); v[3]  = bf_hi(f0.y);
        v[4]  = bf_lo(f0.z); v[5]  = bf_hi(f0.z);
        v[6]  = bf_lo(f0.w); v[7]  = bf_hi(f0.w);
        v[8]  = bf_lo(f1.x); v[9]  = bf_hi(f1.x);
        v[10] = bf_lo(f1.y); v[11] = bf_hi(f1.y);
        v[12] = bf_lo(f1.z); v[13] = bf_hi(f1.z);
        v[14] = bf_lo(f1.w); v[15] = bf_hi(f1.w);
    }

    float* op = out + (((long)b * kCOut) << kCells64Log) + cell;
    #pragma unroll
    for (int c = 0; c < kCOut; ++c) op[(long)c << kCells64Log] = v[c];
}

extern "C" void kernel_launch(void* const* d_in, const int* in_sizes, int n_in,
                              void* d_out, int out_size, void* d_ws, size_t ws_size,
                              hipStream_t stream)
{
    const float* x  = (const float*)d_in[0];
    const float* W1 = (const float*)d_in[1];
    const float* b1 = (const float*)d_in[2];
    const float* W2 = (const float*)d_in[3];
    const float* b2 = (const float*)d_in[4];
    const int* perm = (const int*)d_in[5];

    float* out32 = (float*)d_out;
    float* out64 = out32 + kOut32Elems;

    // ws layout:
    //  [W1p 2KB][W2t 8KB][pad->16KB]
    //  [prec 16.8MB][partial32 32MB][win64 u64 33.5MB][feat 67MB]  ~150MB
    float* W1p = (float*)d_ws;
    float* W2t = W1p + kCMid * 4;
    unsigned long long* prec = (unsigned long long*)((char*)d_ws + 16384);
    unsigned int* partial32 = (unsigned int*)(prec + (size_t)kB * kN);
    unsigned long long* win64 =
        (unsigned long long*)(partial32 + (size_t)kB * kChunks32 * kCells32);
    uint4* feat = (uint4*)(win64 + (size_t)kB * kCells64);

    const int nPtsBlocks  = (int)(((long)kB * kN) / 256);        // 8192
    const int nPairBlocks = (int)(((long)kB * kN) / 512);        // 4096
    const int n32Blocks   = (int)(((long)kB * kCells32) / 256);  // 2048
    const int n64Blocks   = (int)(((long)kB * kCells64) / 256);  // 16384
    dim3 blk(256);

    k_pack<<<1, 256, 0, stream>>>(W1, b1, W2, W1p, W2t);
    k_prec<<<nPtsBlocks, blk, 0, stream>>>(x, perm, prec);
    k_mlp<<<nPairBlocks, blk, 0, stream>>>(x, W1p, W2t, b2, feat);

    k_win32<<<kB * kChunks32, 1024, 0, stream>>>(prec, partial32);
    k_win64<<<kB * kSlabs64, 1024, 0, stream>>>(prec, win64);

    k_gather32<<<n32Blocks, blk, 0, stream>>>(partial32, perm, feat, out32);
    k_gather64<<<n64Blocks, blk, 0, stream>>>(win64, feat, out64);
}

// Round 10
// 299.028 us; speedup vs baseline: 1.0565x; 1.0565x over previous
//
#include <hip/hip_runtime.h>

namespace {
constexpr int kB = 16;
constexpr int kN = 131072;            // 2^17
constexpr int kNLog = 17;
constexpr int kCMid = 128;
constexpr int kCOut = 16;
constexpr int kCells32Log = 15;       // 32^3
constexpr int kCells64Log = 18;       // 64^3
constexpr int kCells32 = 1 << kCells32Log;
constexpr int kCells64 = 1 << kCells64Log;
constexpr long kOut32Elems = (long)kB * kCOut * kCells32;
constexpr int kChunks32 = 16;         // point-chunks per batch for win32
constexpr int kSlabs64 = 16;          // ix-slabs per batch for win64
constexpr int kSlabCells = kCells64 / kSlabs64;  // 16384
}  // namespace

typedef __bf16 bf16x8 __attribute__((ext_vector_type(8)));
typedef float f32x4 __attribute__((ext_vector_type(4)));

__device__ inline unsigned int packbf2(float lo, float hi) {
    // RNE-round both to bf16, pack (hi<<16)|lo.
    unsigned int a = __float_as_uint(lo);
    unsigned int b = __float_as_uint(hi);
    a = (a + 0x7FFFu + ((a >> 16) & 1u)) >> 16;
    b = (b + 0x7FFFu + ((b >> 16) & 1u)) & 0xFFFF0000u;
    return b | a;
}
__device__ inline float bf_lo(unsigned int p) { return __uint_as_float(p << 16); }
__device__ inline float bf_hi(unsigned int p) { return __uint_as_float(p & 0xFFFF0000u); }

__device__ inline uint4 pack8(const float* h) {
    uint4 r;
    r.x = packbf2(h[0], h[1]); r.y = packbf2(h[2], h[3]);
    r.z = packbf2(h[4], h[5]); r.w = packbf2(h[6], h[7]);
    return r;
}

// ---------------------------------------------------------------------------
// Stage packed weights:
//  W1p[k][4]  = (w0,w1,w2,b1k)                         (f32, 2 KB)
//  w2h/w2l[kw*64+lane] = A-fragment of W2 for MFMA 16x16x32, bf16 hi/lo split:
//     lane l supplies A[ch=l&15][k=kw*32+(l>>4)*8+e], e=0..7 (8 bf16 = uint4).
// ---------------------------------------------------------------------------
__global__ __launch_bounds__(256) void k_pack(
    const float* __restrict__ W1, const float* __restrict__ b1,
    const float* __restrict__ W2,
    float* __restrict__ W1p, uint4* __restrict__ w2h, uint4* __restrict__ w2l)
{
    const int t = threadIdx.x;
    for (int k = t; k < kCMid; k += 256) {
        W1p[k * 4 + 0] = W1[k * 3 + 0];
        W1p[k * 4 + 1] = W1[k * 3 + 1];
        W1p[k * 4 + 2] = W1[k * 3 + 2];
        W1p[k * 4 + 3] = b1[k];
    }
    // t = kw*64 + lane
    {
        const int kw = t >> 6;
        const int lane = t & 63;
        const int ch = lane & 15;
        const int grp = lane >> 4;
        float v[8], lo[8];
        #pragma unroll
        for (int e = 0; e < 8; ++e)
            v[e] = W2[ch * kCMid + kw * 32 + grp * 8 + e];
        const uint4 hh = pack8(v);
        lo[0] = v[0] - bf_lo(hh.x); lo[1] = v[1] - bf_hi(hh.x);
        lo[2] = v[2] - bf_lo(hh.y); lo[3] = v[3] - bf_hi(hh.y);
        lo[4] = v[4] - bf_lo(hh.z); lo[5] = v[5] - bf_hi(hh.z);
        lo[6] = v[6] - bf_lo(hh.w); lo[7] = v[7] - bf_hi(hh.w);
        w2h[t] = hh;
        w2l[t] = pack8(lo);
    }
}

// ---------------------------------------------------------------------------
// Permuted-order precompute (NO atomics): for (b,i): j=perm[b,i];
// prec[b][j] = cell64<<33 | cell32<<18 | (i+1).  (pri fits 18 bits)
// Cell math: __fmul_rn/__fadd_rn (no FMA contraction) matches numpy exactly.
// ---------------------------------------------------------------------------
__global__ __launch_bounds__(256) void k_prec(
    const float* __restrict__ x,
    const int* __restrict__ perm,
    unsigned long long* __restrict__ prec)
{
    const long gid = (long)blockIdx.x * 256 + threadIdx.x;  // over B*N permuted
    const long bbase = gid & ~(long)(kN - 1);               // b*kN
    const int i = (int)(gid & (kN - 1));
    const int j = perm[gid];

    const float* xp = x + (bbase + j) * 3;
    const float v0 = xp[0], v1 = xp[1], v2 = xp[2];

    const int ix32 = (int)fminf(fmaxf(__fadd_rn(__fmul_rn(v0, 32.0f), 16.5f), 0.0f), 31.0f);
    const int iy32 = (int)fminf(fmaxf(__fadd_rn(__fmul_rn(v1, 32.0f), 16.5f), 0.0f), 31.0f);
    const int iz32 = (int)fminf(fmaxf(__fadd_rn(__fmul_rn(v2, 32.0f), 16.5f), 0.0f), 31.0f);
    const int ix64 = (int)fminf(fmaxf(__fadd_rn(__fmul_rn(v0, 64.0f), 32.5f), 0.0f), 63.0f);
    const int iy64 = (int)fminf(fmaxf(__fadd_rn(__fmul_rn(v1, 64.0f), 32.5f), 0.0f), 63.0f);
    const int iz64 = (int)fminf(fmaxf(__fadd_rn(__fmul_rn(v2, 64.0f), 32.5f), 0.0f), 63.0f);

    const unsigned long long cell32 = (unsigned long long)((ix32 * 32 + iy32) * 32 + iz32);
    const unsigned long long cell64 = (unsigned long long)((ix64 * 64 + iy64) * 64 + iz64);
    prec[bbase + j] = (cell64 << 33) | (cell32 << 18) | (unsigned long long)(i + 1);
}

// ---------------------------------------------------------------------------
// MFMA MLP, natural order. Each wave owns 64 points (4 N-tiles of 16).
// Layer-1 computed DIRECTLY in B-fragment layout: lane l computes
// h[k=kw*32+(l>>4)*8+e] of point (tile*16 + (l&15)) -- no LDS transpose.
// Layer-2: D[16ch x 16pt] = W2 . h via mfma_f32_16x16x32_bf16, bf16 hi/lo
// split on BOTH operands (3 MFMAs, lo*lo dropped) to keep f32-level accuracy.
// C/D layout (m89): pt = lane&15, ch = (lane>>4)*4 + reg.
// Epilogue: +b2, pack 4 ch -> 8B store; 512B/wave contiguous per tile.
// ---------------------------------------------------------------------------
__global__ __launch_bounds__(256, 4) void k_mlp(
    const float* __restrict__ x,
    const float* __restrict__ W1p,
    const uint4* __restrict__ w2h, const uint4* __restrict__ w2l,
    const float* __restrict__ b2,
    uint2* __restrict__ feat)          // 4 uint2 per point (16 bf16)
{
    const int tid = threadIdx.x;
    const int lane = tid & 63;
    const int grp = lane >> 4;          // 0..3
    const int pt16 = lane & 15;
    const long base = (((long)blockIdx.x << 2) + (tid >> 6)) << 6;  // wave*64

    // x for this wave's 4 point-tiles (4 lanes share each point -> L1 bcast)
    float xv[4][3];
    #pragma unroll
    for (int t = 0; t < 4; ++t) {
        const float* xp = x + (base + t * 16 + pt16) * 3;
        xv[t][0] = xp[0]; xv[t][1] = xp[1]; xv[t][2] = xp[2];
    }

    f32x4 acc[4];
    #pragma unroll
    for (int t = 0; t < 4; ++t) acc[t] = (f32x4){0.f, 0.f, 0.f, 0.f};

    const float4* __restrict__ w1v = (const float4*)W1p;

    #pragma unroll
    for (int kw = 0; kw < 4; ++kw) {
        const bf16x8 ah = __builtin_bit_cast(bf16x8, w2h[(kw << 6) + lane]);
        const bf16x8 al = __builtin_bit_cast(bf16x8, w2l[(kw << 6) + lane]);
        // this lane's 8 W1 rows: k = kw*32 + grp*8 + e (16 lanes share -> L1)
        float4 w1r[8];
        #pragma unroll
        for (int e = 0; e < 8; ++e)
            w1r[e] = w1v[(kw << 5) + (grp << 3) + e];

        #pragma unroll
        for (int t = 0; t < 4; ++t) {
            float h[8], lo[8];
            #pragma unroll
            for (int e = 0; e < 8; ++e)
                h[e] = fmaxf(fmaf(w1r[e].x, xv[t][0],
                              fmaf(w1r[e].y, xv[t][1],
                               fmaf(w1r[e].z, xv[t][2], w1r[e].w))), 0.0f);
            const uint4 bh = pack8(h);
            lo[0] = h[0] - bf_lo(bh.x); lo[1] = h[1] - bf_hi(bh.x);
            lo[2] = h[2] - bf_lo(bh.y); lo[3] = h[3] - bf_hi(bh.y);
            lo[4] = h[4] - bf_lo(bh.z); lo[5] = h[5] - bf_hi(bh.z);
            lo[6] = h[6] - bf_lo(bh.w); lo[7] = h[7] - bf_hi(bh.w);
            const uint4 bl4 = pack8(lo);
            const bf16x8 bhv = __builtin_bit_cast(bf16x8, bh);
            const bf16x8 blv = __builtin_bit_cast(bf16x8, bl4);
            acc[t] = __builtin_amdgcn_mfma_f32_16x16x32_bf16(ah, bhv, acc[t], 0, 0, 0);
            acc[t] = __builtin_amdgcn_mfma_f32_16x16x32_bf16(ah, blv, acc[t], 0, 0, 0);
            acc[t] = __builtin_amdgcn_mfma_f32_16x16x32_bf16(al, bhv, acc[t], 0, 0, 0);
        }
    }

    const float4 bias = ((const float4*)b2)[grp];   // channels grp*4..grp*4+3
    #pragma unroll
    for (int t = 0; t < 4; ++t) {
        const float c0 = acc[t][0] + bias.x;
        const float c1 = acc[t][1] + bias.y;
        const float c2 = acc[t][2] + bias.z;
        const float c3 = acc[t][3] + bias.w;
        uint2 o;
        o.x = packbf2(c0, c1);
        o.y = packbf2(c2, c3);
        feat[((base + t * 16 + pt16) << 2) + grp] = o;
    }
}

// ---------------------------------------------------------------------------
// win32 via LDS: block = (batch b, point-chunk c). Full 32768-cell winner
// array (u32 pri tokens) in 128 KB LDS; ds-atomicMax per point; plain
// coalesced writeout of the partial. Merge happens inline in k_gather32.
// ---------------------------------------------------------------------------
__global__ __launch_bounds__(1024) void k_win32(
    const unsigned long long* __restrict__ prec,
    unsigned int* __restrict__ partial32)
{
    __shared__ unsigned int lwin[kCells32];   // 128 KB
    const int b = blockIdx.x >> 4;
    const int c = blockIdx.x & (kChunks32 - 1);
    const int t = threadIdx.x;

    #pragma unroll
    for (int r = 0; r < kCells32 / 1024; ++r) lwin[r * 1024 + t] = 0u;
    __syncthreads();

    const long base = ((long)b << kNLog) + (long)c * (kN / kChunks32);
    #pragma unroll
    for (int r = 0; r < (kN / kChunks32) / 1024; ++r) {   // 8 iters
        const unsigned long long w = prec[base + r * 1024 + t];
        atomicMax(&lwin[(int)((w >> 18) & 0x7FFFull)], (unsigned int)(w & 0x3FFFFull));
    }
    __syncthreads();

    unsigned int* dst = partial32 + ((long)blockIdx.x << kCells32Log);
    #pragma unroll
    for (int r = 0; r < kCells32 / 1024; ++r) dst[r * 1024 + t] = lwin[r * 1024 + t];
}

// ---------------------------------------------------------------------------
// win64 via LDS slabs: block = (batch b, slab s of 16384 contiguous cells).
// u64 tokens (pri<<32)|j in 128 KB LDS; block rescans its batch's prec
// (1 MB, L2/L3-resident), filters to its slab, LDS-atomics, exclusive
// coalesced writeout. No merge, no zero, no global atomics.
// ---------------------------------------------------------------------------
__global__ __launch_bounds__(1024) void k_win64(
    const unsigned long long* __restrict__ prec,
    unsigned long long* __restrict__ win64)
{
    __shared__ unsigned long long lwin[kSlabCells];   // 128 KB
    const int b = blockIdx.x >> 4;
    const int s = blockIdx.x & (kSlabs64 - 1);
    const int t = threadIdx.x;

    #pragma unroll
    for (int r = 0; r < kSlabCells / 1024; ++r) lwin[r * 1024 + t] = 0ull;
    __syncthreads();

    const long base = (long)b << kNLog;
    for (int r = 0; r < kN / 1024; ++r) {             // 128 iters
        const int j = r * 1024 + t;
        const unsigned long long w = prec[base + j];
        const int cell = (int)(w >> 33);
        if ((cell >> 14) == s)
            atomicMax(&lwin[cell & (kSlabCells - 1)],
                      ((w & 0x3FFFFull) << 32) | (unsigned long long)(unsigned int)j);
    }
    __syncthreads();

    unsigned long long* dst = win64 + ((long)b << kCells64Log) + ((long)s << 14);
    #pragma unroll
    for (int r = 0; r < kSlabCells / 1024; ++r) dst[r * 1024 + t] = lwin[r * 1024 + t];
}

// ---------------------------------------------------------------------------
// gather32 with inline 16-way partial merge: w = max_c partial32[b][c][cell];
// i = w-1 -> j = perm[b,i] (L2 hop) -> feat[b,j]. Full rewrite every call.
// ---------------------------------------------------------------------------
__global__ __launch_bounds__(256) void k_gather32(
    const unsigned int* __restrict__ partial32,
    const int* __restrict__ perm,
    const uint4* __restrict__ feat,
    float* __restrict__ out)
{
    const long gid = (long)blockIdx.x * 256 + threadIdx.x;  // over B*cells32
    const int b = (int)(gid >> kCells32Log);
    const int cell = (int)(gid & (kCells32 - 1));

    unsigned int w = 0u;
    #pragma unroll
    for (int c = 0; c < kChunks32; ++c)
        w = max(w, partial32[(((long)(b * kChunks32 + c)) << kCells32Log) + cell]);

    float v[kCOut];
    #pragma unroll
    for (int c = 0; c < kCOut; ++c) v[c] = 0.0f;

    if (w != 0u) {
        const int i = (int)(w - 1u);
        const int j = perm[((long)b << kNLog) + i];
        const long pidx = ((long)b << kNLog) + j;
        const uint4 f0 = feat[pidx * 2 + 0];
        const uint4 f1 = feat[pidx * 2 + 1];
        v[0]  = bf_lo(f0.x); v[1]  = bf_hi(f0.x);
        v[2]  = bf_lo(f0.y); v[3]  = bf_hi(f0.y);
        v[4]  = bf_lo(f0.z); v[5]  = bf_hi(f0.z);
        v[6]  = bf_lo(f0.w); v[7]  = bf_hi(f0.w);
        v[8]  = bf_lo(f1.x); v[9]  = bf_hi(f1.x);
        v[10] = bf_lo(f1.y); v[11] = bf_hi(f1.y);
        v[12] = bf_lo(f1.z); v[13] = bf_hi(f1.z);
        v[14] = bf_lo(f1.w); v[15] = bf_hi(f1.w);
    }

    float* op = out + (((long)b * kCOut) << kCells32Log) + cell;
    #pragma unroll
    for (int c = 0; c < kCOut; ++c) op[(long)c << kCells32Log] = v[c];
}

// ---------------------------------------------------------------------------
// gather64: token (pri<<32)|j coalesced; j -> feat[b,j] (random 32B,
// L3-resident); write 16 channels (zeros if empty).
// ---------------------------------------------------------------------------
__global__ __launch_bounds__(256) void k_gather64(
    const unsigned long long* __restrict__ win,
    const uint4* __restrict__ feat,
    float* __restrict__ out)
{
    const long gid = (long)blockIdx.x * 256 + threadIdx.x;  // over B*cells64
    const int b = (int)(gid >> kCells64Log);
    const int cell = (int)(gid & (kCells64 - 1));
    const unsigned long long w = win[gid];

    float v[kCOut];
    #pragma unroll
    for (int c = 0; c < kCOut; ++c) v[c] = 0.0f;

    if (w != 0ull) {
        const int j = (int)(w & 0xFFFFFFFFull);
        const long pidx = ((long)b << kNLog) + j;
        const uint4 f0 = feat[pidx * 2 + 0];
        const uint4 f1 = feat[pidx * 2 + 1];
        v[0]  = bf_lo(f0.x); v[1]  = bf_hi(f0.x);
        v[2]  = bf_lo(f0.y); v[3]  = bf_hi(f0.y);
        v[4]  = bf_lo(f0.z); v[5]  = bf_hi(f0.z);
        v[6]  = bf_lo(f0.w); v[7]  = bf_hi(f0.w);
        v[8]  = bf_lo(f1.x); v[9]  = bf_hi(f1.x);
        v[10] = bf_lo(f1.y); v[11] = bf_hi(f1.y);
        v[12] = bf_lo(f1.z); v[13] = bf_hi(f1.z);
        v[14] = bf_lo(f1.w); v[15] = bf_hi(f1.w);
    }

    float* op = out + (((long)b * kCOut) << kCells64Log) + cell;
    #pragma unroll
    for (int c = 0; c < kCOut; ++c) op[(long)c << kCells64Log] = v[c];
}

extern "C" void kernel_launch(void* const* d_in, const int* in_sizes, int n_in,
                              void* d_out, int out_size, void* d_ws, size_t ws_size,
                              hipStream_t stream)
{
    const float* x  = (const float*)d_in[0];
    const float* W1 = (const float*)d_in[1];
    const float* b1 = (const float*)d_in[2];
    const float* W2 = (const float*)d_in[3];
    const float* b2 = (const float*)d_in[4];
    const int* perm = (const int*)d_in[5];

    float* out32 = (float*)d_out;
    float* out64 = out32 + kOut32Elems;

    // ws layout:
    //  [W1p 2KB][w2h 4KB][w2l 4KB][pad->16KB]
    //  [prec 16.8MB][partial32 32MB][win64 u64 33.5MB][feat 67MB]  ~150MB
    float* W1p = (float*)d_ws;
    uint4* w2h = (uint4*)((char*)d_ws + 2048);
    uint4* w2l = w2h + 256;
    unsigned long long* prec = (unsigned long long*)((char*)d_ws + 16384);
    unsigned int* partial32 = (unsigned int*)(prec + (size_t)kB * kN);
    unsigned long long* win64 =
        (unsigned long long*)(partial32 + (size_t)kB * kChunks32 * kCells32);
    uint4* feat = (uint4*)(win64 + (size_t)kB * kCells64);

    const int nPtsBlocks = (int)(((long)kB * kN) / 256);        // 8192
    const int n32Blocks  = (int)(((long)kB * kCells32) / 256);  // 2048
    const int n64Blocks  = (int)(((long)kB * kCells64) / 256);  // 16384
    dim3 blk(256);

    k_pack<<<1, 256, 0, stream>>>(W1, b1, W2, W1p, w2h, w2l);
    k_prec<<<nPtsBlocks, blk, 0, stream>>>(x, perm, prec);
    k_mlp<<<nPtsBlocks, blk, 0, stream>>>(x, W1p, w2h, w2l, b2, (uint2*)feat);

    k_win32<<<kB * kChunks32, 1024, 0, stream>>>(prec, partial32);
    k_win64<<<kB * kSlabs64, 1024, 0, stream>>>(prec, win64);

    k_gather32<<<n32Blocks, blk, 0, stream>>>(partial32, perm, feat, out32);
    k_gather64<<<n64Blocks, blk, 0, stream>>>(win64, feat, out64);
}